// Round 6
// baseline (444.260 us; speedup 1.0000x reference)
//
#include <hip/hip_runtime.h>
#include <cstdint>
#include <cstddef>

// PositionalEncoderGrid: Instant-NGP multiresolution hash grid.
// B=524288 points, L=16 levels, T=2^19 entries/level, F=2 floats.
//
// R6 (= R5 with compile fix): phase A is L2-capacity bound (FETCH 362MB vs
// 70MB compulsory; ILP was neutral). Level pairing {15-j, j} per XCD is
// optimal but working sets are 4.0-6.1MB vs 4MB L2, and the ws/out store
// streams write-allocate and evict table lines. Nontemporal stores (ws, out)
// + nontemporal loads of ws in phase B keep the streams from polluting L2 so
// table lines stay resident. Nontemporal builtins require scalar or NATIVE
// vector types: float2 goes through double, float4 through ext_vector_type.

#define NUM_LEVELS 16
#define TBL_MASK ((1u << 19) - 1u)
#define PRIME_Y 2654435761u
#define PRIME_Z 805459861u
#define BATCH 524288

typedef float nfloat4 __attribute__((ext_vector_type(4)));

__constant__ float c_ns[NUM_LEVELS] = {
    16.f, 20.f, 25.f, 32.f, 40.f, 50.f, 64.f, 80.f,
    101.f, 128.f, 161.f, 203.f, 256.f, 322.f, 406.f, 512.f
};

struct Corner8 {
    uint32_t i[8];
    float wx0, wy0, wz0;
};

__device__ __forceinline__ float2 d2f2(double d) {
    union { double d; float2 f; } u;
    u.d = d;
    return u.f;
}

__device__ __forceinline__ double f22d(float2 f) {
    union { double d; float2 f; } u;
    u.f = f;
    return u.d;
}

__device__ __forceinline__ Corner8 corner_setup(
    const float* __restrict__ in, int p, float n)
{
    const float vx = in[p * 3 + 0];
    const float vy = in[p * 3 + 1];
    const float vz = in[p * 3 + 2];

    const float xs = (vx + 3.0f) / 6.0f;
    const float ys = (vy + 3.0f) / 6.0f;
    const float zs = (vz + 3.0f) / 6.0f;

    const float tx = xs * n, ty = ys * n, tz = zs * n;
    const float fpx = floorf(tx), fpy = floorf(ty), fpz = floorf(tz);

    Corner8 c;
    c.wx0 = tx - fpx;   // fractional part (weight for offset=1 axis)
    c.wy0 = ty - fpy;
    c.wz0 = tz - fpz;

    const uint32_t px = (uint32_t)fpx;
    const uint32_t py = (uint32_t)fpy;
    const uint32_t pz = (uint32_t)fpz;

    const uint32_t hx0 = px;
    const uint32_t hx1 = px + 1u;
    const uint32_t hy0 = py * PRIME_Y;
    const uint32_t hy1 = hy0 + PRIME_Y;
    const uint32_t hz0 = pz * PRIME_Z;
    const uint32_t hz1 = hz0 + PRIME_Z;

    c.i[0] = (hx0 ^ hy0 ^ hz0) & TBL_MASK;
    c.i[1] = (hx0 ^ hy0 ^ hz1) & TBL_MASK;
    c.i[2] = (hx0 ^ hy1 ^ hz0) & TBL_MASK;
    c.i[3] = (hx0 ^ hy1 ^ hz1) & TBL_MASK;
    c.i[4] = (hx1 ^ hy0 ^ hz0) & TBL_MASK;
    c.i[5] = (hx1 ^ hy0 ^ hz1) & TBL_MASK;
    c.i[6] = (hx1 ^ hy1 ^ hz0) & TBL_MASK;
    c.i[7] = (hx1 ^ hy1 ^ hz1) & TBL_MASK;
    return c;
}

__device__ __forceinline__ float2 blend(const Corner8& c, const float2 f[8])
{
    const float wx1 = c.wx0, wx0 = 1.0f - c.wx0;
    const float wy1 = c.wy0, wy0 = 1.0f - c.wy0;
    const float wz1 = c.wz0, wz0 = 1.0f - c.wz0;

    float a0 = 0.0f, a1 = 0.0f, w;
    w = wx0 * wy0 * wz0; a0 = fmaf(f[0].x, w, a0); a1 = fmaf(f[0].y, w, a1);
    w = wx0 * wy0 * wz1; a0 = fmaf(f[1].x, w, a0); a1 = fmaf(f[1].y, w, a1);
    w = wx0 * wy1 * wz0; a0 = fmaf(f[2].x, w, a0); a1 = fmaf(f[2].y, w, a1);
    w = wx0 * wy1 * wz1; a0 = fmaf(f[3].x, w, a0); a1 = fmaf(f[3].y, w, a1);
    w = wx1 * wy0 * wz0; a0 = fmaf(f[4].x, w, a0); a1 = fmaf(f[4].y, w, a1);
    w = wx1 * wy0 * wz1; a0 = fmaf(f[5].x, w, a0); a1 = fmaf(f[5].y, w, a1);
    w = wx1 * wy1 * wz0; a0 = fmaf(f[6].x, w, a0); a1 = fmaf(f[6].y, w, a1);
    w = wx1 * wy1 * wz1; a0 = fmaf(f[7].x, w, a0); a1 = fmaf(f[7].y, w, a1);
    return make_float2(a0, a1);
}

// Phase A: level-major compute into ws[l*B + p]; 2 points per thread.
// Nontemporal ws stores: don't let the 64MB stream evict table lines.
__global__ __launch_bounds__(256) void enc_level_major_kernel(
    const float* __restrict__ in,
    const float* __restrict__ table,
    double* __restrict__ ws)           // [L, B] float2 as double
{
    const int v = blockIdx.x & 15;              // level slot -> XCD v%8
    const int chunk = blockIdx.x >> 4;          // 1024 chunks of 512 points
    const int l = (v < 8) ? (15 - v) : (v - 8); // fine+coarse paired per XCD
    const int p0 = chunk * 512 + threadIdx.x;
    const int p1 = p0 + 256;

    const float n = c_ns[l];
    const Corner8 cA = corner_setup(in, p0, n);
    const Corner8 cB = corner_setup(in, p1, n);

    const double* __restrict__ tb =
        ((const double*)table) + ((size_t)l << 19);   // 8B entries

    float2 fA[8], fB[8];
    if (l >= 2) {
#pragma unroll
        for (int k = 0; k < 8; ++k)
            fA[k] = d2f2(__builtin_nontemporal_load(&tb[cA.i[k]]));
#pragma unroll
        for (int k = 0; k < 8; ++k)
            fB[k] = d2f2(__builtin_nontemporal_load(&tb[cB.i[k]]));
    } else {
#pragma unroll
        for (int k = 0; k < 8; ++k) fA[k] = d2f2(tb[cA.i[k]]);
#pragma unroll
        for (int k = 0; k < 8; ++k) fB[k] = d2f2(tb[cB.i[k]]);
    }

    __builtin_nontemporal_store(f22d(blend(cA, fA)), &ws[(size_t)l * BATCH + p0]);
    __builtin_nontemporal_store(f22d(blend(cB, fB)), &ws[(size_t)l * BATCH + p1]);
}

// Phase B: transpose [L,B] float2 -> [B,8] float4. One thread per output
// float4 (coalesced 16B lane writes); nt on both sides — pure streaming.
__global__ __launch_bounds__(256) void transpose_kernel(
    const double* __restrict__ ws,     // [L, B] float2 as double
    nfloat4* __restrict__ out)         // [B*8] native float4
{
    const int gid = blockIdx.x * 256 + threadIdx.x;  // 0 .. B*8-1
    const int p = gid >> 3;
    const int j = gid & 7;

    const float2 a = d2f2(__builtin_nontemporal_load(&ws[(size_t)(2 * j) * BATCH + p]));
    const float2 b = d2f2(__builtin_nontemporal_load(&ws[(size_t)(2 * j + 1) * BATCH + p]));
    nfloat4 r;
    r.x = a.x; r.y = a.y; r.z = b.x; r.w = b.y;
    __builtin_nontemporal_store(r, &out[gid]);
}

// Fallback: direct scatter store (no workspace needed).
__global__ __launch_bounds__(256) void enc_scatter_kernel(
    const float* __restrict__ in,
    const float* __restrict__ table,
    float2* __restrict__ out)          // [B, 16] float2
{
    const int v = blockIdx.x & 15;
    const int chunk = blockIdx.x >> 4;
    const int l = (v < 8) ? (15 - v) : (v - 8);
    const int p = chunk * 256 + threadIdx.x;

    const float n = c_ns[l];
    const Corner8 c = corner_setup(in, p, n);
    const double* __restrict__ tb = ((const double*)table) + ((size_t)l << 19);
    float2 f[8];
#pragma unroll
    for (int k = 0; k < 8; ++k) f[k] = d2f2(tb[c.i[k]]);
    out[(size_t)p * NUM_LEVELS + l] = blend(c, f);
}

extern "C" void kernel_launch(void* const* d_in, const int* in_sizes, int n_in,
                              void* d_out, int out_size, void* d_ws, size_t ws_size,
                              hipStream_t stream) {
    const float* inputs = (const float*)d_in[0];   // [B,3] fp32
    const float* table  = (const float*)d_in[1];   // [16, 2^19, 2] fp32

    const size_t ws_needed = (size_t)NUM_LEVELS * BATCH * sizeof(float2); // 64 MiB

    if (ws_size >= ws_needed) {
        double* ws = (double*)d_ws;
        // 16 level-slots x 1024 chunks (512 points each) = 16384 blocks
        enc_level_major_kernel<<<16384, 256, 0, stream>>>(inputs, table, ws);
        // B*8 float4 outputs / 256 = 16384 blocks
        transpose_kernel<<<16384, 256, 0, stream>>>(ws, (nfloat4*)d_out);
    } else {
        enc_scatter_kernel<<<32768, 256, 0, stream>>>(inputs, table, (float2*)d_out);
    }
}

// Round 7
// 430.987 us; speedup vs baseline: 1.0308x; 1.0308x over previous
//
#include <hip/hip_runtime.h>
#include <cstdint>
#include <cstddef>

// PositionalEncoderGrid: Instant-NGP multiresolution hash grid.
// B=524288 points, L=16 levels, T=2^19 entries/level, F=2 floats.
//
// R7: - Phase A: 8 equal-work slots (slot=blockIdx&7 -> XCD). Each block
//       processes 256 points for BOTH paired levels {15-slot, slot}; the
//       pairing keeps each XCD's table working set minimal (reversed-sort
//       matching is optimal) and equal work kills the coarse/fine tail that
//       held achieved occupancy at 55%. nt table loads (l>=2) + nt ws stores.
//     - Phase B: LDS-tiled transpose. Dense 2KB per-level reads into
//       lds[256][17] (pad -> <=4-way bank aliasing), then 256x128B fully
//       coalesced nt float4 writes. Replaces the 16-way interleaved 64B
//       segment pattern that ran at ~1/4 of stream BW.

#define NUM_LEVELS 16
#define TBL_MASK ((1u << 19) - 1u)
#define PRIME_Y 2654435761u
#define PRIME_Z 805459861u
#define BATCH 524288

typedef float nfloat4 __attribute__((ext_vector_type(4)));

__constant__ float c_ns[NUM_LEVELS] = {
    16.f, 20.f, 25.f, 32.f, 40.f, 50.f, 64.f, 80.f,
    101.f, 128.f, 161.f, 203.f, 256.f, 322.f, 406.f, 512.f
};

struct Corner8 {
    uint32_t i[8];
    float wx0, wy0, wz0;
};

__device__ __forceinline__ float2 d2f2(double d) {
    union { double d; float2 f; } u;
    u.d = d;
    return u.f;
}

__device__ __forceinline__ double f22d(float2 f) {
    union { double d; float2 f; } u;
    u.f = f;
    return u.d;
}

// Corner indices + fractional weights for one (already-normalized) point at
// resolution n.
__device__ __forceinline__ Corner8 corner_setup_xyz(
    float xs, float ys, float zs, float n)
{
    const float tx = xs * n, ty = ys * n, tz = zs * n;
    const float fpx = floorf(tx), fpy = floorf(ty), fpz = floorf(tz);

    Corner8 c;
    c.wx0 = tx - fpx;
    c.wy0 = ty - fpy;
    c.wz0 = tz - fpz;

    const uint32_t px = (uint32_t)fpx;
    const uint32_t py = (uint32_t)fpy;
    const uint32_t pz = (uint32_t)fpz;

    const uint32_t hx0 = px;
    const uint32_t hx1 = px + 1u;
    const uint32_t hy0 = py * PRIME_Y;
    const uint32_t hy1 = hy0 + PRIME_Y;
    const uint32_t hz0 = pz * PRIME_Z;
    const uint32_t hz1 = hz0 + PRIME_Z;

    c.i[0] = (hx0 ^ hy0 ^ hz0) & TBL_MASK;
    c.i[1] = (hx0 ^ hy0 ^ hz1) & TBL_MASK;
    c.i[2] = (hx0 ^ hy1 ^ hz0) & TBL_MASK;
    c.i[3] = (hx0 ^ hy1 ^ hz1) & TBL_MASK;
    c.i[4] = (hx1 ^ hy0 ^ hz0) & TBL_MASK;
    c.i[5] = (hx1 ^ hy0 ^ hz1) & TBL_MASK;
    c.i[6] = (hx1 ^ hy1 ^ hz0) & TBL_MASK;
    c.i[7] = (hx1 ^ hy1 ^ hz1) & TBL_MASK;
    return c;
}

__device__ __forceinline__ float2 blend(const Corner8& c, const float2 f[8])
{
    const float wx1 = c.wx0, wx0 = 1.0f - c.wx0;
    const float wy1 = c.wy0, wy0 = 1.0f - c.wy0;
    const float wz1 = c.wz0, wz0 = 1.0f - c.wz0;

    float a0 = 0.0f, a1 = 0.0f, w;
    w = wx0 * wy0 * wz0; a0 = fmaf(f[0].x, w, a0); a1 = fmaf(f[0].y, w, a1);
    w = wx0 * wy0 * wz1; a0 = fmaf(f[1].x, w, a0); a1 = fmaf(f[1].y, w, a1);
    w = wx0 * wy1 * wz0; a0 = fmaf(f[2].x, w, a0); a1 = fmaf(f[2].y, w, a1);
    w = wx0 * wy1 * wz1; a0 = fmaf(f[3].x, w, a0); a1 = fmaf(f[3].y, w, a1);
    w = wx1 * wy0 * wz0; a0 = fmaf(f[4].x, w, a0); a1 = fmaf(f[4].y, w, a1);
    w = wx1 * wy0 * wz1; a0 = fmaf(f[5].x, w, a0); a1 = fmaf(f[5].y, w, a1);
    w = wx1 * wy1 * wz0; a0 = fmaf(f[6].x, w, a0); a1 = fmaf(f[6].y, w, a1);
    w = wx1 * wy1 * wz1; a0 = fmaf(f[7].x, w, a0); a1 = fmaf(f[7].y, w, a1);
    return make_float2(a0, a1);
}

// Phase A: each block handles 256 points for both levels of one XCD pair
// {15-slot, slot}. Equal work per block -> no coarse/fine tail.
__global__ __launch_bounds__(256) void enc_pair_kernel(
    const float* __restrict__ in,
    const float* __restrict__ table,
    double* __restrict__ ws)           // [L, B] float2 as double
{
    const int slot = blockIdx.x & 7;           // -> XCD slot
    const int chunk = blockIdx.x >> 3;         // 2048 chunks of 256 points
    const int lf = 15 - slot;                  // fine level
    const int lc = slot;                       // coarse level
    const int p = chunk * 256 + threadIdx.x;

    const float vx = in[p * 3 + 0];
    const float vy = in[p * 3 + 1];
    const float vz = in[p * 3 + 2];
    const float xs = (vx + 3.0f) / 6.0f;
    const float ys = (vy + 3.0f) / 6.0f;
    const float zs = (vz + 3.0f) / 6.0f;

    const Corner8 cF = corner_setup_xyz(xs, ys, zs, c_ns[lf]);
    const Corner8 cC = corner_setup_xyz(xs, ys, zs, c_ns[lc]);

    const double* __restrict__ tbF = ((const double*)table) + ((size_t)lf << 19);
    const double* __restrict__ tbC = ((const double*)table) + ((size_t)lc << 19);

    // All 16 gathers in flight before first use.
    float2 fF[8], fC[8];
#pragma unroll
    for (int k = 0; k < 8; ++k)
        fF[k] = d2f2(__builtin_nontemporal_load(&tbF[cF.i[k]]));
    if (lc >= 2) {
#pragma unroll
        for (int k = 0; k < 8; ++k)
            fC[k] = d2f2(__builtin_nontemporal_load(&tbC[cC.i[k]]));
    } else {
#pragma unroll
        for (int k = 0; k < 8; ++k) fC[k] = d2f2(tbC[cC.i[k]]);
    }

    __builtin_nontemporal_store(f22d(blend(cF, fF)), &ws[(size_t)lf * BATCH + p]);
    __builtin_nontemporal_store(f22d(blend(cC, fC)), &ws[(size_t)lc * BATCH + p]);
}

// Phase B: LDS-tiled transpose [L,B] -> [B,L]. Block stages 256 points x 16
// levels (dense 2KB reads per level), writes 256x128B coalesced.
__global__ __launch_bounds__(256) void transpose_kernel(
    const double* __restrict__ ws,     // [L, B] float2 as double
    nfloat4* __restrict__ out)         // [B*8]
{
    __shared__ double lds[256][NUM_LEVELS + 1];   // +1 pad: 34B-row stride

    const int tid = threadIdx.x;
    const int p0 = blockIdx.x * 256;

#pragma unroll
    for (int l = 0; l < NUM_LEVELS; ++l) {
        lds[tid][l] = __builtin_nontemporal_load(&ws[(size_t)l * BATCH + p0 + tid]);
    }
    __syncthreads();

    // 2048 float4s per block; lane-contiguous stores.
#pragma unroll
    for (int it = 0; it < 8; ++it) {
        const int e = it * 256 + tid;
        const int p = e >> 3;          // point within tile
        const int j = e & 7;           // float4 index within point
        const float2 a = d2f2(lds[p][2 * j]);
        const float2 b = d2f2(lds[p][2 * j + 1]);
        nfloat4 r;
        r.x = a.x; r.y = a.y; r.z = b.x; r.w = b.y;
        __builtin_nontemporal_store(r, &out[(size_t)blockIdx.x * 2048 + e]);
    }
}

// Fallback: direct scatter store (no workspace needed).
__global__ __launch_bounds__(256) void enc_scatter_kernel(
    const float* __restrict__ in,
    const float* __restrict__ table,
    float2* __restrict__ out)          // [B, 16] float2
{
    const int v = blockIdx.x & 15;
    const int chunk = blockIdx.x >> 4;
    const int l = (v < 8) ? (15 - v) : (v - 8);
    const int p = chunk * 256 + threadIdx.x;

    const float vx = in[p * 3 + 0];
    const float vy = in[p * 3 + 1];
    const float vz = in[p * 3 + 2];
    const Corner8 c = corner_setup_xyz((vx + 3.0f) / 6.0f, (vy + 3.0f) / 6.0f,
                                       (vz + 3.0f) / 6.0f, c_ns[l]);
    const double* __restrict__ tb = ((const double*)table) + ((size_t)l << 19);
    float2 f[8];
#pragma unroll
    for (int k = 0; k < 8; ++k) f[k] = d2f2(tb[c.i[k]]);
    out[(size_t)p * NUM_LEVELS + l] = blend(c, f);
}

extern "C" void kernel_launch(void* const* d_in, const int* in_sizes, int n_in,
                              void* d_out, int out_size, void* d_ws, size_t ws_size,
                              hipStream_t stream) {
    const float* inputs = (const float*)d_in[0];   // [B,3] fp32
    const float* table  = (const float*)d_in[1];   // [16, 2^19, 2] fp32

    const size_t ws_needed = (size_t)NUM_LEVELS * BATCH * sizeof(float2); // 64 MiB

    if (ws_size >= ws_needed) {
        double* ws = (double*)d_ws;
        // Phase A: 8 slots x 2048 chunks = 16384 blocks, 256 pts x 2 levels each.
        enc_pair_kernel<<<16384, 256, 0, stream>>>(inputs, table, ws);
        // Phase B: 524288/256 = 2048 blocks.
        transpose_kernel<<<2048, 256, 0, stream>>>(ws, (nfloat4*)d_out);
    } else {
        enc_scatter_kernel<<<32768, 256, 0, stream>>>(inputs, table, (float2*)d_out);
    }
}